// Round 5
// baseline (153.249 us; speedup 1.0000x reference)
//
#include <hip/hip_runtime.h>

#define NLAYERS 4
#define BATCH   64
#define LEN1    256
#define LEN2    256
#define DIM     1024
#define BKK     64
#define NKT     (DIM / BKK)   // 16 K-tiles
#define PITCH   64            // halfs per LDS row (128 B), XOR-swizzled chunks

typedef _Float16 f16x8 __attribute__((ext_vector_type(8)));
typedef float    f32x4 __attribute__((ext_vector_type(4)));

// ---------------------------------------------------------------------------
// Kernel 1: one 1024-thread block per (nl, b) — 16 waves, 4x4 wave grid, each
// wave owns a 64x64 output sub-tile.  A and B each read from global exactly
// once.  f16 MFMA on unnormalized dots, fp32 sums-of-squares during staging,
// epilogue normalizes + masked max/mean -> F1.
// LDS: row = 128 B = 8 chunks of 16 B; chunk swizzle pc = c ^ (row & 7)
// applied on BOTH ds_write and ds_read -> no 4-way bank conflicts.
// Double-buffered, loads for tile k+1 in flight across tile k's MFMA,
// ONE barrier per K-tile (16 total).
// ---------------------------------------------------------------------------
__global__ __launch_bounds__(1024, 4)
void bs_main(const float* __restrict__ reps1, const float* __restrict__ reps2,
             const int* __restrict__ len1, const int* __restrict__ len2,
             float* __restrict__ feat) {
  __shared__ _Float16 Ah[2][LEN1 * PITCH];   // 2 x 32 KB
  __shared__ _Float16 Bh[2][LEN2 * PITCH];   // 2 x 32 KB
  __shared__ float ssq1[LEN1];
  __shared__ float ssq2[LEN2];
  __shared__ float rowp[LEN1][4];            // per-row max partials (by wn)
  __shared__ float colp[LEN2][4];            // per-col max partials (by wm)
  __shared__ float redbuf[32];

  const int bid = blockIdx.x;
  const int nl  = bid >> 6;
  const int bb  = bid & 63;
  const float* gA = reps1 + (size_t)bid * LEN1 * DIM;
  const float* gB = reps2 + (size_t)bid * LEN2 * DIM;

  const int tid  = threadIdx.x;
  const int lane = tid & 63;
  const int wid  = tid >> 6;     // 16 waves
  const int wm   = wid >> 2;     // 0..3  (M, 64 rows each)
  const int wn   = wid & 3;      // 0..3  (N, 64 cols each)
  const int li   = lane & 15;
  const int lh   = lane >> 4;

  f32x4 acc[4][4];
  #pragma unroll
  for (int a = 0; a < 4; ++a)
    #pragma unroll
    for (int c = 0; c < 4; ++c) acc[a][c] = 0.0f;

  float pssqA = 0.f, pssqB = 0.f;
  const int rS = tid >> 2;            // 0..255 : staged row (A and B)
  const int cq = tid & 3;             // 0..3   : 16-float group within row

  float4 ra[4], rb[4];

  auto issue_loads = [&](int kt) {
    const float4* a4 = (const float4*)(gA + (size_t)rS * DIM + kt * BKK + cq * 16);
    ra[0] = a4[0];  ra[1] = a4[1];  ra[2] = a4[2];  ra[3] = a4[3];
    const float4* b4 = (const float4*)(gB + (size_t)rS * DIM + kt * BKK + cq * 16);
    rb[0] = b4[0];  rb[1] = b4[1];  rb[2] = b4[2];  rb[3] = b4[3];
  };

  // swizzled half-offsets for this thread's two 16B chunks (row-invariant)
  const int pc0 = ((2 * cq)     ^ (rS & 7)) * 8;
  const int pc1 = ((2 * cq + 1) ^ (rS & 7)) * 8;

  auto convert_write = [&](int buf) {
    {
      f16x8 h0, h1;
      float s = 0.f;
      #pragma unroll
      for (int q = 0; q < 2; ++q) {
        const float f0 = ra[2*q].x,   f1 = ra[2*q].y,   f2 = ra[2*q].z,   f3 = ra[2*q].w;
        const float f4 = ra[2*q+1].x, f5 = ra[2*q+1].y, f6 = ra[2*q+1].z, f7 = ra[2*q+1].w;
        s += f0*f0 + f1*f1 + f2*f2 + f3*f3 + f4*f4 + f5*f5 + f6*f6 + f7*f7;
        f16x8& hv = q ? h1 : h0;
        hv[0] = (_Float16)f0; hv[1] = (_Float16)f1; hv[2] = (_Float16)f2; hv[3] = (_Float16)f3;
        hv[4] = (_Float16)f4; hv[5] = (_Float16)f5; hv[6] = (_Float16)f6; hv[7] = (_Float16)f7;
      }
      pssqA += s;
      *(f16x8*)&Ah[buf][rS * PITCH + pc0] = h0;
      *(f16x8*)&Ah[buf][rS * PITCH + pc1] = h1;
    }
    {
      f16x8 h0, h1;
      float s = 0.f;
      #pragma unroll
      for (int q = 0; q < 2; ++q) {
        const float f0 = rb[2*q].x,   f1 = rb[2*q].y,   f2 = rb[2*q].z,   f3 = rb[2*q].w;
        const float f4 = rb[2*q+1].x, f5 = rb[2*q+1].y, f6 = rb[2*q+1].z, f7 = rb[2*q+1].w;
        s += f0*f0 + f1*f1 + f2*f2 + f3*f3 + f4*f4 + f5*f5 + f6*f6 + f7*f7;
        f16x8& hv = q ? h1 : h0;
        hv[0] = (_Float16)f0; hv[1] = (_Float16)f1; hv[2] = (_Float16)f2; hv[3] = (_Float16)f3;
        hv[4] = (_Float16)f4; hv[5] = (_Float16)f5; hv[6] = (_Float16)f6; hv[7] = (_Float16)f7;
      }
      pssqB += s;
      *(f16x8*)&Bh[buf][rS * PITCH + pc0] = h0;
      *(f16x8*)&Bh[buf][rS * PITCH + pc1] = h1;
    }
  };

  issue_loads(0);
  convert_write(0);
  __syncthreads();

  for (int kt = 0; kt < NKT; ++kt) {
    const int cur = kt & 1;
    const bool more = (kt + 1 < NKT);
    if (more) issue_loads(kt + 1);   // in flight across the MFMA phase

    const _Float16* AhC = Ah[cur];
    const _Float16* BhC = Bh[cur];
    #pragma unroll
    for (int ks = 0; ks < 2; ++ks) {
      f16x8 af[4];
      #pragma unroll
      for (int fm = 0; fm < 4; ++fm) {
        const int r = wm * 64 + fm * 16 + li;
        const int g = ks * 4 + lh;
        af[fm] = *(const f16x8*)&AhC[r * PITCH + (g ^ (r & 7)) * 8];
      }
      #pragma unroll
      for (int fn = 0; fn < 4; ++fn) {
        const int r = wn * 64 + fn * 16 + li;
        const int g = ks * 4 + lh;
        const f16x8 bf = *(const f16x8*)&BhC[r * PITCH + (g ^ (r & 7)) * 8];
        #pragma unroll
        for (int fm = 0; fm < 4; ++fm)
          acc[fm][fn] = __builtin_amdgcn_mfma_f32_16x16x32_f16(af[fm], bf, acc[fm][fn], 0, 0, 0);
      }
    }

    if (more) convert_write(cur ^ 1);
    __syncthreads();
  }

  // ---- norms: deterministic 4-thread-per-row shuffle reduce, direct store
  pssqA += __shfl_xor(pssqA, 1, 64);
  pssqA += __shfl_xor(pssqA, 2, 64);
  pssqB += __shfl_xor(pssqB, 1, 64);
  pssqB += __shfl_xor(pssqB, 2, 64);
  if (cq == 0) {
    ssq1[rS] = pssqA;
    ssq2[rS] = pssqB;
  }
  __syncthreads();
  if (tid < 256)       ssq1[tid] = 1.0f / sqrtf(ssq1[tid]);
  else if (tid < 512)  ssq2[tid - 256] = 1.0f / sqrtf(ssq2[tid - 256]);
  __syncthreads();

  const int n1 = len1[bb];
  const int n2 = len2[bb];

  float rn2v[4];
  bool  jv[4];
  #pragma unroll
  for (int fn = 0; fn < 4; ++fn) {
    const int j = wn * 64 + fn * 16 + li;
    rn2v[fn] = ssq2[j];
    jv[fn]   = (j < n2);
  }
  float rn1v[4][4];
  bool  iv[4][4];
  #pragma unroll
  for (int fm = 0; fm < 4; ++fm)
    #pragma unroll
    for (int rg = 0; rg < 4; ++rg) {
      const int i = wm * 64 + fm * 16 + lh * 4 + rg;
      rn1v[fm][rg] = ssq1[i];
      iv[fm][rg]   = (i < n1);
    }

  const float NEG = -3.402823466e38f;
  float rowm[4][4];
  float colm[4];
  #pragma unroll
  for (int fm = 0; fm < 4; ++fm)
    #pragma unroll
    for (int rg = 0; rg < 4; ++rg) rowm[fm][rg] = NEG;
  #pragma unroll
  for (int fn = 0; fn < 4; ++fn) colm[fn] = NEG;

  #pragma unroll
  for (int fm = 0; fm < 4; ++fm)
    #pragma unroll
    for (int fn = 0; fn < 4; ++fn)
      #pragma unroll
      for (int rg = 0; rg < 4; ++rg) {
        const float v = acc[fm][fn][rg] * rn1v[fm][rg] * rn2v[fn];
        if (jv[fn] && v > rowm[fm][rg]) rowm[fm][rg] = v;
        if (iv[fm][rg] && v > colm[fn]) colm[fn] = v;
      }

  // row maxima: reduce across li (lane bits 0..3)
  #pragma unroll
  for (int m = 1; m <= 8; m <<= 1)
    #pragma unroll
    for (int fm = 0; fm < 4; ++fm)
      #pragma unroll
      for (int rg = 0; rg < 4; ++rg) {
        const float o = __shfl_xor(rowm[fm][rg], m, 64);
        rowm[fm][rg] = fmaxf(rowm[fm][rg], o);
      }
  // col maxima: reduce across lh (lane bits 4..5)
  #pragma unroll
  for (int m = 16; m <= 32; m <<= 1)
    #pragma unroll
    for (int fn = 0; fn < 4; ++fn) {
      const float o = __shfl_xor(colm[fn], m, 64);
      colm[fn] = fmaxf(colm[fn], o);
    }

  if (li == 0)
    #pragma unroll
    for (int fm = 0; fm < 4; ++fm)
      #pragma unroll
      for (int rg = 0; rg < 4; ++rg)
        rowp[wm * 64 + fm * 16 + lh * 4 + rg][wn] = rowm[fm][rg];
  if (lh == 0)
    #pragma unroll
    for (int fn = 0; fn < 4; ++fn)
      colp[wn * 64 + fn * 16 + li][wm] = colm[fn];
  __syncthreads();

  float c1 = 0.f, c2 = 0.f;
  if (tid < 256) {
    const float rm = fmaxf(fmaxf(rowp[tid][0], rowp[tid][1]),
                           fmaxf(rowp[tid][2], rowp[tid][3]));
    if (tid < n1) c2 = rm;
    const float cm = fmaxf(fmaxf(colp[tid][0], colp[tid][1]),
                           fmaxf(colp[tid][2], colp[tid][3]));
    if (tid < n2) c1 = cm;
  }
  #pragma unroll
  for (int m = 1; m <= 32; m <<= 1) {
    c1 += __shfl_xor(c1, m, 64);
    c2 += __shfl_xor(c2, m, 64);
  }
  if (lane == 0) {
    redbuf[wid]      = c1;
    redbuf[16 + wid] = c2;
  }
  __syncthreads();
  if (tid == 0) {
    float s1s = 0.f, s2s = 0.f;
    #pragma unroll
    for (int i = 0; i < 16; ++i) { s1s += redbuf[i]; s2s += redbuf[16 + i]; }
    const float s1 = s1s / (float)n2;
    const float s2 = s2s / (float)n1;
    feat[bb * NLAYERS + nl] = 2.0f * s1 * s2 / (s1 + s2);
  }
}

// ---------------------------------------------------------------------------
// Kernel 2: BatchNorm1d (batch stats, biased var) + linear head -> out[b]
// ---------------------------------------------------------------------------
__global__ void bs_head(const float* __restrict__ feat, const float* __restrict__ w,
                        const float* __restrict__ bias, float* __restrict__ out) {
  __shared__ float lds[NLAYERS][BATCH];
  const int tid = threadIdx.x;
  const int nl  = tid >> 6;
  const int b   = tid & 63;

  const float x = feat[b * NLAYERS + nl];
  float s = x;
  #pragma unroll
  for (int m = 1; m <= 32; m <<= 1) s += __shfl_xor(s, m, 64);
  const float mean = s / 64.0f;
  const float d = x - mean;
  float v = d * d;
  #pragma unroll
  for (int m = 1; m <= 32; m <<= 1) v += __shfl_xor(v, m, 64);
  const float var = v / 64.0f;
  const float y = d / sqrtf(var + 1e-8f);

  lds[nl][b] = y * w[nl];
  __syncthreads();
  if (tid < 64)
    out[tid] = lds[0][tid] + lds[1][tid] + lds[2][tid] + lds[3][tid] + bias[0];
}

extern "C" void kernel_launch(void* const* d_in, const int* in_sizes, int n_in,
                              void* d_out, int out_size, void* d_ws, size_t ws_size,
                              hipStream_t stream) {
  const float* reps1 = (const float*)d_in[0];
  const float* reps2 = (const float*)d_in[1];
  const int*   len1  = (const int*)d_in[2];
  const int*   len2  = (const int*)d_in[3];
  const float* w     = (const float*)d_in[4];
  const float* bias  = (const float*)d_in[5];
  float* feat = (float*)d_ws;   // 256 floats

  bs_main<<<NLAYERS * BATCH, 1024, 0, stream>>>(reps1, reps2, len1, len2, feat);
  bs_head<<<1, 256, 0, stream>>>(feat, w, bias, (float*)d_out);
}